// Round 1
// 687.665 us; speedup vs baseline: 2.7499x; 2.7499x over previous
//
#include <hip/hip_runtime.h>
#include <math.h>

// GatedMDTA: B=2, C=192, H=W=256, HEADS=6, hd=32, QC=768.
// I/O dtype = fp32. Internals: bf16 MFMA 16x16x32 for the three GEMM-shaped
// ops, bf16 workspace intermediates, fp32 everywhere else. m89/m91 layouts:
//   A[m=lane&15][k=quad*8+j], B[k=quad*8+j][n=lane&15], D: col=lane&15, row=quad*4+reg.
// Round 6: dwconv_ssq rewritten from latency-bound 1-row/block scalar-tap
// version (290us/dispatch, 2.7% HBM, 7.7% VALUBusy) to LDS row-tiled version:
// one block per (channel, 32-row group), 34 staged rows in LDS, ushort4
// global I/O, ds_read_b64 + shfl for horizontal taps. Everything else
// unchanged from the 1890us round-5 kernel.

#define HEADS 6
#define CDIM 192
#define QCH 768
#define HH 256
#define WW 256
#define NPIX 65536

typedef __bf16 bf16x8 __attribute__((ext_vector_type(8)));
typedef float f32x4 __attribute__((ext_vector_type(4)));

__device__ __forceinline__ float b2f(unsigned short u) {
  union { unsigned int i; float f; } x; x.i = ((unsigned int)u) << 16; return x.f;
}
__device__ __forceinline__ unsigned short f2b(float f) {
  union { float f; unsigned int i; } x; x.f = f;
  unsigned int lsb = (x.i >> 16) & 1u;
  x.i += 0x7fffu + lsb;           // round-to-nearest-even
  return (unsigned short)(x.i >> 16);
}

// ---------------- zero-init small fp32 scratch (replaces hipMemsetAsync)
__global__ void zero_init(float* __restrict__ p, int n) {
  int i = blockIdx.x * 256 + threadIdx.x;
  if (i < n) p[i] = 0.f;
}

// ---------------- GEMM + bias: out[m][n] = sum_k A[m][k]*B[k][n] + bias[m]
// M=192 (one qkv quarter / proj), K=192, N=65536. Tile 64x64, 4 waves.
template <bool IN_F32, bool OUT_F32>
__global__ __launch_bounds__(256)
void gemm_bias(const float* __restrict__ A,      // [192][192] fp32 weights
               const void* __restrict__ Bm,      // [192][N] fp32 or bf16
               const float* __restrict__ bias,   // [192] fp32
               void* __restrict__ out)           // [192][N] fp32 or bf16
{
  const int K = 192;
  const int N = NPIX;
  int m0 = blockIdx.x * 64;
  int n0 = blockIdx.y * 64;

  __shared__ unsigned short a_lds[64][200];  // pad 192->200 (2-way alias = free)
  __shared__ unsigned short b_lds[64][200];  // n-major: b_lds[n][k]
  int t = threadIdx.x;

  // A tile: 64 rows x 192 floats, cast to bf16 into LDS
  #pragma unroll
  for (int i = 0; i < 12; ++i) {
    int idx = t + i * 256;                 // 0..3071
    int row = idx / 48, c4 = idx - row * 48;
    float4 v = *(const float4*)(A + (size_t)(m0 + row) * K + c4 * 4);
    unsigned short* dst = &a_lds[row][c4 * 4];
    dst[0] = f2b(v.x); dst[1] = f2b(v.y); dst[2] = f2b(v.z); dst[3] = f2b(v.w);
  }
  // B tile transposed on the fly (coalesced global reads over n)
  #pragma unroll
  for (int i = 0; i < 48; ++i) {
    int idx = t + i * 256;                 // 0..12287
    int n = idx & 63, k = idx >> 6;
    float v;
    if (IN_F32) v = ((const float*)Bm)[(size_t)k * N + n0 + n];
    else        v = b2f(((const unsigned short*)Bm)[(size_t)k * N + n0 + n]);
    b_lds[n][k] = f2b(v);
  }
  __syncthreads();

  int wid = t >> 6, lane = t & 63;
  int r = lane & 15, quad = lane >> 4;
  f32x4 acc[4];
  #pragma unroll
  for (int nt = 0; nt < 4; ++nt) acc[nt] = (f32x4){0.f, 0.f, 0.f, 0.f};

  #pragma unroll
  for (int kk = 0; kk < 192; kk += 32) {
    bf16x8 af = *(const bf16x8*)(&a_lds[wid * 16 + r][kk + quad * 8]);
    #pragma unroll
    for (int nt = 0; nt < 4; ++nt) {
      bf16x8 bfr = *(const bf16x8*)(&b_lds[nt * 16 + r][kk + quad * 8]);
      acc[nt] = __builtin_amdgcn_mfma_f32_16x16x32_bf16(af, bfr, acc[nt], 0, 0, 0);
    }
  }

  #pragma unroll
  for (int nt = 0; nt < 4; ++nt) {
    int col = n0 + nt * 16 + r;
    #pragma unroll
    for (int i = 0; i < 4; ++i) {
      int row = m0 + wid * 16 + quad * 4 + i;
      float v = acc[nt][i] + bias[row];
      if (OUT_F32) ((float*)out)[(size_t)row * N + col] = v;
      else ((unsigned short*)out)[(size_t)row * N + col] = f2b(v);
    }
  }
}

// ---------------- 3x3 depthwise conv + bias over one 192-channel quarter;
// optional fused per-channel sum-of-squares (for q,k).
// Round-6 structure: block = (channel o, 32-row group). 34 input rows staged
// in LDS via coalesced ushort4 loads; wave w computes rows w*8..w*8+7, lane l
// computes columns 4l..4l+3 (wave spans the full 256-px row, so horizontal
// neighbors come from shfl within the wave; x boundaries are lanes 0/63).
__global__ __launch_bounds__(256)
void dwconv_ssq(const unsigned short* __restrict__ in,   // [192][H][W] bf16
                const float* __restrict__ w9,            // [192][9] fp32
                const float* __restrict__ bias,          // [192] fp32
                unsigned short* __restrict__ outp,       // [192][H][W] bf16
                float* __restrict__ ssq)                 // [192] or nullptr
{
  __shared__ unsigned short lds[34][256];   // rows y0-1 .. y0+32
  __shared__ float red[4];
  int t = threadIdx.x;
  int o  = blockIdx.x >> 3;                 // channel 0..191
  int ry = blockIdx.x & 7;                  // row group 0..7
  int y0 = ry << 5;                         // first output row

  const unsigned short* base = in + (size_t)o * NPIX;
  // stage 34 rows x 256 cols = 2176 ushort4 chunks, 8B/lane coalesced
  #pragma unroll
  for (int i = 0; i < 9; ++i) {
    int idx = t + i * 256;
    if (idx < 2176) {
      int row = idx >> 6;
      int c4  = (idx & 63) << 2;
      int gy  = y0 - 1 + row;
      ushort4 vv = make_ushort4(0, 0, 0, 0);       // zero-pad y boundary
      if (gy >= 0 && gy < HH)
        vv = *(const ushort4*)(base + (size_t)gy * WW + c4);
      *(ushort4*)(&lds[row][c4]) = vv;
    }
  }

  float wv[9];
  #pragma unroll
  for (int i = 0; i < 9; ++i) wv[i] = w9[o * 9 + i];
  float bo = bias[o];
  __syncthreads();

  int w = t >> 6, lane = t & 63;
  int x0 = lane << 2;                       // 4 columns per lane
  float sumsq = 0.f;
  unsigned short* outbase = outp + (size_t)o * NPIX;

  #pragma unroll
  for (int i = 0; i < 8; ++i) {
    int yo = w * 8 + i;                     // local output row (0..31)
    float a0 = bo, a1 = bo, a2 = bo, a3 = bo;
    #pragma unroll
    for (int dy = 0; dy < 3; ++dy) {
      // input row for this tap: lds row (yo + dy)  <-> global row y0+yo-1+dy
      ushort4 mv = *(const ushort4*)(&lds[yo + dy][x0]);   // ds_read_b64
      float v0 = b2f(mv.x), v1 = b2f(mv.y), v2 = b2f(mv.z), v3 = b2f(mv.w);
      float vl = __shfl_up(v3, 1, 64);   if (lane == 0)  vl = 0.f;  // x=-1
      float vr = __shfl_down(v0, 1, 64); if (lane == 63) vr = 0.f;  // x=256
      float w0 = wv[dy * 3 + 0], w1 = wv[dy * 3 + 1], w2 = wv[dy * 3 + 2];
      a0 += w0 * vl + w1 * v0 + w2 * v1;
      a1 += w0 * v0 + w1 * v1 + w2 * v2;
      a2 += w0 * v1 + w1 * v2 + w2 * v3;
      a3 += w0 * v2 + w1 * v3 + w2 * vr;
    }
    ushort4 ov;
    ov.x = f2b(a0); ov.y = f2b(a1); ov.z = f2b(a2); ov.w = f2b(a3);
    *(ushort4*)(outbase + (size_t)(y0 + yo) * WW + x0) = ov;    // 8B store
    if (ssq != nullptr) sumsq += a0 * a0 + a1 * a1 + a2 * a2 + a3 * a3;
  }

  if (ssq != nullptr) {                     // uniform per launch
    #pragma unroll
    for (int off = 32; off; off >>= 1) sumsq += __shfl_down(sumsq, off, 64);
    if (lane == 0) red[w] = sumsq;
    __syncthreads();
    if (t == 0) atomicAdd(&ssq[o], red[0] + red[1] + red[2] + red[3]);
  }
}

// ---------------- Gram: S[h][c][d] = sum_n q[h*32+c,n]*k[h*32+d,n]
__global__ __launch_bounds__(256)
void gram(const unsigned short* __restrict__ q,   // [192][N] bf16
          const unsigned short* __restrict__ k,   // [192][N] bf16
          float* __restrict__ S)                  // [HEADS][32][32]
{
  int h = blockIdx.y;
  int t = threadIdx.x, wid = t >> 6, lane = t & 63;
  int r = lane & 15, quad = lane >> 4;
  int c0 = (wid >> 1) * 16, d0 = (wid & 1) * 16;
  size_t nb = (size_t)blockIdx.x * 2048 + quad * 8;
  const unsigned short* qrow = q + (size_t)(h * 32 + c0 + r) * NPIX + nb;
  const unsigned short* krow = k + (size_t)(h * 32 + d0 + r) * NPIX + nb;
  f32x4 acc = (f32x4){0.f, 0.f, 0.f, 0.f};
  #pragma unroll 8
  for (int kk = 0; kk < 2048; kk += 32) {
    bf16x8 af  = *(const bf16x8*)(qrow + kk);
    bf16x8 bfr = *(const bf16x8*)(krow + kk);
    acc = __builtin_amdgcn_mfma_f32_16x16x32_bf16(af, bfr, acc, 0, 0, 0);
  }
  float* Sp = S + (size_t)h * 1024;
  #pragma unroll
  for (int i = 0; i < 4; ++i)
    atomicAdd(&Sp[(c0 + quad * 4 + i) * 32 + (d0 + r)], acc[i]);
}

// ---------------- scale by 1/(|q||k|)*temp, softmax over d (32-wide)
__global__ void softmax_scale(const float* __restrict__ S,      // [HEADS][1024]
                              const float* __restrict__ ssq_q,  // [192]
                              const float* __restrict__ ssq_k,  // [192]
                              const float* __restrict__ temp,   // [HEADS] fp32
                              float* __restrict__ P)            // [HEADS][1024]
{
  int h = blockIdx.x;
  int t = threadIdx.x;
  int c = t >> 5, d = t & 31;
  float nq = fmaxf(sqrtf(ssq_q[h * 32 + c]), 1e-12f);
  float nk = fmaxf(sqrtf(ssq_k[h * 32 + d]), 1e-12f);
  float v = S[(size_t)h * 1024 + t] / (nq * nk) * temp[h];
  float m = v;
  for (int off = 16; off; off >>= 1) m = fmaxf(m, __shfl_xor(m, off, 32));
  float e = expf(v - m);
  float s = e;
  for (int off = 16; off; off >>= 1) s += __shfl_xor(s, off, 32);
  P[(size_t)h * 1024 + t] = e / s;
}

// ---------------- att[c,n] = (sum_d P[c,d]*v[d,n]) * sigmoid(gate[c,n])
__global__ __launch_bounds__(256)
void pv_gate(const unsigned short* __restrict__ v,  // [192][N] bf16
             const unsigned short* __restrict__ g,  // [192][N] bf16
             const float* __restrict__ P,           // [HEADS][1024]
             unsigned short* __restrict__ att)      // [192][N] bf16
{
  int h = blockIdx.y;
  size_t n = (size_t)blockIdx.x * 256 + threadIdx.x;
  const unsigned short* vb = v + (size_t)(h * 32) * NPIX + n;
  const unsigned short* gb = g + (size_t)(h * 32) * NPIX + n;
  __shared__ float Ps[1024];
  for (int i = threadIdx.x; i < 1024; i += 256) Ps[i] = P[(size_t)h * 1024 + i];
  __syncthreads();
  float vr[32];
  #pragma unroll
  for (int d = 0; d < 32; ++d) vr[d] = b2f(vb[(size_t)d * NPIX]);
  unsigned short* outb = att + (size_t)(h * 32) * NPIX + n;
  #pragma unroll
  for (int c = 0; c < 32; ++c) {
    float a = 0.f;
    #pragma unroll
    for (int d = 0; d < 32; ++d) a += Ps[c * 32 + d] * vr[d];
    float gg = b2f(gb[(size_t)c * NPIX]);
    float sg = 1.f / (1.f + expf(-gg));
    outb[(size_t)c * NPIX] = f2b(a * sg);
  }
}

extern "C" void kernel_launch(void* const* d_in, const int* in_sizes, int n_in,
                              void* d_out, int out_size, void* d_ws, size_t ws_size,
                              hipStream_t stream)
{
  const float* x      = (const float*)d_in[0];
  const float* qkv_w  = (const float*)d_in[1];
  const float* qkv_b  = (const float*)d_in[2];
  const float* dw_w   = (const float*)d_in[3];
  const float* dw_b   = (const float*)d_in[4];
  const float* temp   = (const float*)d_in[5];
  const float* proj_w = (const float*)d_in[6];
  const float* proj_b = (const float*)d_in[7];
  float* out = (float*)d_out;

  // workspace: 3 x 25.2 MB bf16 buffers + S[2][6][1024] + ssq[2][2][192] + P[6][1024]
  char* ws = (char*)d_ws;
  const size_t qbytes = (size_t)CDIM * NPIX * 2;   // 25,165,824
  unsigned short* bufA = (unsigned short*)ws;                 // pre / att
  unsigned short* bufB = (unsigned short*)(ws + qbytes);      // post_q, later post_v
  unsigned short* bufC = (unsigned short*)(ws + 2 * qbytes);  // post_k, later post_gate
  float* S   = (float*)(ws + 3 * qbytes);      // 2*6*1024 floats
  float* ssq = S + 2 * HEADS * 1024;           // 2*2*192 floats
  float* P   = ssq + 2 * 2 * CDIM;             // 6*1024 floats (reused per batch)
  const int nz = 2 * HEADS * 1024 + 2 * 2 * CDIM;   // S + ssq
  zero_init<<<(nz + 255) / 256, 256, 0, stream>>>(S, nz);

  const dim3 ggrid(CDIM / 64, NPIX / 64);
  const int qw = CDIM * CDIM;   // quarter offset in qkv_w elements

  for (int b = 0; b < 2; ++b) {
    const float* xb = x + (size_t)b * CDIM * NPIX;
    float* outb = out + (size_t)b * CDIM * NPIX;
    float* Sb = S + (size_t)b * HEADS * 1024;
    float* sq = ssq + (size_t)b * 2 * CDIM;        // |q|^2 per channel
    float* sk = sq + CDIM;                         // |k|^2 per channel

    // q quarter (rows 0..191) -> bufB
    gemm_bias<true, false><<<ggrid, 256, 0, stream>>>(qkv_w + 0 * qw, xb, qkv_b + 0 * CDIM, bufA);
    dwconv_ssq<<<CDIM * 8, 256, 0, stream>>>(bufA, dw_w + 0 * CDIM * 9, dw_b + 0 * CDIM, bufB, sq);
    // k quarter (rows 384..575) -> bufC
    gemm_bias<true, false><<<ggrid, 256, 0, stream>>>(qkv_w + 2 * qw, xb, qkv_b + 2 * CDIM, bufA);
    dwconv_ssq<<<CDIM * 8, 256, 0, stream>>>(bufA, dw_w + 2 * CDIM * 9, dw_b + 2 * CDIM, bufC, sk);

    gram<<<dim3(32, HEADS), 256, 0, stream>>>(bufB, bufC, Sb);
    softmax_scale<<<HEADS, 1024, 0, stream>>>(Sb, sq, sk, temp, P);

    // v quarter (rows 576..767) -> bufB
    gemm_bias<true, false><<<ggrid, 256, 0, stream>>>(qkv_w + 3 * qw, xb, qkv_b + 3 * CDIM, bufA);
    dwconv_ssq<<<CDIM * 8, 256, 0, stream>>>(bufA, dw_w + 3 * CDIM * 9, dw_b + 3 * CDIM, bufB, nullptr);
    // gate quarter (rows 192..383) -> bufC
    gemm_bias<true, false><<<ggrid, 256, 0, stream>>>(qkv_w + 1 * qw, xb, qkv_b + 1 * CDIM, bufA);
    dwconv_ssq<<<CDIM * 8, 256, 0, stream>>>(bufA, dw_w + 1 * CDIM * 9, dw_b + 1 * CDIM, bufC, nullptr);

    // att -> bufA (pre_gate dead)
    pv_gate<<<dim3(NPIX / 256, HEADS), 256, 0, stream>>>(bufB, bufC, P, bufA);
    // proj -> fp32 out
    gemm_bias<false, true><<<ggrid, 256, 0, stream>>>(proj_w, bufA, proj_b, outb);
  }
}

// Round 2
// 616.090 us; speedup vs baseline: 3.0693x; 1.1162x over previous
//
#include <hip/hip_runtime.h>
#include <math.h>

// GatedMDTA: B=2, C=192, H=W=256, HEADS=6, hd=32, QC=768.
// Round 7: dispatch-structure collapse. 29 launches -> 10 via blockIdx.z
// batch/quarter merging; x pre-converted to bf16 once (kills f2b VALU storm +
// halves qkv B-read bytes); gram grid.x 32->128 (192 -> 1536 blocks).
// All numerics bitwise-identical to round 6 (f2b applied once in x2bf instead
// of per-tile; b2f->f2b roundtrip on bf16 is identity).
//
// ws layout (qbytes = 192*65536*2 = 25,165,824 B; ws >= 384 MiB):
//   xbf   [2q]  @ 0          x in bf16, per batch
//   pre   [4q]  @ 2q         gemm out (pre-conv), reused for VG phase, then att
//   post  [4q]  @ 6q         post-conv q,k   (z = b*2 + {0:q,1:k})
//   post2 [4q]  @ 10q        post-conv v,gate(z = b*2 + {0:v,1:g})
//   floats @ 14q: S[2][6][1024], ssq[2][2][192], P[2][6][1024]

#define HEADS 6
#define CDIM 192
#define QCH 768
#define HH 256
#define WW 256
#define NPIX 65536

typedef __bf16 bf16x8 __attribute__((ext_vector_type(8)));
typedef float f32x4 __attribute__((ext_vector_type(4)));

__device__ __forceinline__ float b2f(unsigned short u) {
  union { unsigned int i; float f; } x; x.i = ((unsigned int)u) << 16; return x.f;
}
__device__ __forceinline__ unsigned short f2b(float f) {
  union { float f; unsigned int i; } x; x.f = f;
  unsigned int lsb = (x.i >> 16) & 1u;
  x.i += 0x7fffu + lsb;           // round-to-nearest-even
  return (unsigned short)(x.i >> 16);
}

// ---------------- zero-init small fp32 scratch (replaces hipMemsetAsync)
__global__ void zero_init(float* __restrict__ p, int n) {
  int i = blockIdx.x * 256 + threadIdx.x;
  if (i < n) p[i] = 0.f;
}

// ---------------- x fp32 -> bf16, both batches (25.2M elements)
__global__ __launch_bounds__(256)
void x2bf(const float* __restrict__ x, unsigned short* __restrict__ o) {
  const int total = 2 * CDIM * NPIX / 4;          // float4 count = 6291456
  for (int i = blockIdx.x * 256 + threadIdx.x; i < total; i += gridDim.x * 256) {
    float4 v = ((const float4*)x)[i];
    ushort4 u;
    u.x = f2b(v.x); u.y = f2b(v.y); u.z = f2b(v.z); u.w = f2b(v.w);
    ((ushort4*)o)[i] = u;
  }
}

// ---------------- GEMM + bias: out[m][n] = sum_k A[m][k]*B[k][n] + bias[m]
// B always bf16 now. Per z-slice: qsel = (z&1)?qs1:qs0 picks the weight/bias
// quarter; B batch = z>>bShift; out slot = z. M=192/slice, K=192, N=65536.
template <bool OUT_F32>
__global__ __launch_bounds__(256)
void gemm_bias(const float* __restrict__ Aw,     // [4][192][192] or [192][192]
               const float* __restrict__ biasB,  // [4][192] or [192]
               const unsigned short* __restrict__ Bm,  // bf16 [nb][192][N]
               void* __restrict__ outB,          // [z][192][N]
               int qs0, int qs1, int bShift)
{
  const int K = CDIM;
  const int N = NPIX;
  int z = blockIdx.z;
  int qsel = (z & 1) ? qs1 : qs0;
  const float* A    = Aw    + (size_t)qsel * CDIM * CDIM;
  const float* bias = biasB + (size_t)qsel * CDIM;
  const unsigned short* Bu = Bm + (size_t)(z >> bShift) * CDIM * NPIX;

  int m0 = blockIdx.x * 64;
  int n0 = blockIdx.y * 64;

  __shared__ unsigned short a_lds[64][200];  // pad 192->200 (2-way alias = free)
  __shared__ unsigned short b_lds[64][200];  // n-major: b_lds[n][k]
  int t = threadIdx.x;

  // A tile: 64 rows x 192 floats, cast to bf16 into LDS
  #pragma unroll
  for (int i = 0; i < 12; ++i) {
    int idx = t + i * 256;                 // 0..3071
    int row = idx / 48, c4 = idx - row * 48;
    float4 v = *(const float4*)(A + (size_t)(m0 + row) * K + c4 * 4);
    unsigned short* dst = &a_lds[row][c4 * 4];
    dst[0] = f2b(v.x); dst[1] = f2b(v.y); dst[2] = f2b(v.z); dst[3] = f2b(v.w);
  }
  // B tile transposed on the fly: bf16 source, ushort4 (8B/lane) loads
  #pragma unroll
  for (int i = 0; i < 12; ++i) {
    int idx = t + i * 256;                 // 0..3071 vec4 chunks
    int e = idx * 4;                       // element 0..12287
    int n = e & 63, k = e >> 6;            // n multiple of 4
    ushort4 v = *(const ushort4*)(Bu + (size_t)k * N + n0 + n);
    b_lds[n + 0][k] = v.x;
    b_lds[n + 1][k] = v.y;
    b_lds[n + 2][k] = v.z;
    b_lds[n + 3][k] = v.w;
  }
  __syncthreads();

  int wid = t >> 6, lane = t & 63;
  int r = lane & 15, quad = lane >> 4;
  f32x4 acc[4];
  #pragma unroll
  for (int nt = 0; nt < 4; ++nt) acc[nt] = (f32x4){0.f, 0.f, 0.f, 0.f};

  #pragma unroll
  for (int kk = 0; kk < 192; kk += 32) {
    bf16x8 af = *(const bf16x8*)(&a_lds[wid * 16 + r][kk + quad * 8]);
    #pragma unroll
    for (int nt = 0; nt < 4; ++nt) {
      bf16x8 bfr = *(const bf16x8*)(&b_lds[nt * 16 + r][kk + quad * 8]);
      acc[nt] = __builtin_amdgcn_mfma_f32_16x16x32_bf16(af, bfr, acc[nt], 0, 0, 0);
    }
  }

  #pragma unroll
  for (int nt = 0; nt < 4; ++nt) {
    int col = n0 + nt * 16 + r;
    #pragma unroll
    for (int i = 0; i < 4; ++i) {
      int row = m0 + wid * 16 + quad * 4 + i;
      float v = acc[nt][i] + bias[row];
      if (OUT_F32)
        ((float*)outB)[(size_t)z * CDIM * NPIX + (size_t)row * N + col] = v;
      else
        ((unsigned short*)outB)[(size_t)z * CDIM * NPIX + (size_t)row * N + col] = f2b(v);
    }
  }
}

// ---------------- 3x3 depthwise conv + bias; optional fused per-channel ssq.
// block = (channel o, 32-row group); z = quarter-slot (b*2 + which).
__global__ __launch_bounds__(256)
void dwconv_ssq(const unsigned short* __restrict__ in,   // [z][192][H][W] bf16
                const float* __restrict__ w9,            // [4][192][9] fp32
                const float* __restrict__ bias,          // [4][192] fp32
                unsigned short* __restrict__ outp,       // [z][192][H][W] bf16
                float* __restrict__ ssqBase,             // [2][2][192] or null
                int qs0, int qs1)
{
  __shared__ unsigned short lds[34][256];   // rows y0-1 .. y0+32
  __shared__ float red[4];
  int t = threadIdx.x;
  int z = blockIdx.z;
  int qsel = (z & 1) ? qs1 : qs0;
  int o  = blockIdx.x >> 3;                 // channel 0..191
  int ry = blockIdx.x & 7;                  // row group 0..7
  int y0 = ry << 5;                         // first output row

  const unsigned short* base = in + ((size_t)z * CDIM + o) * NPIX;
  // stage 34 rows x 256 cols = 2176 ushort4 chunks, 8B/lane coalesced
  #pragma unroll
  for (int i = 0; i < 9; ++i) {
    int idx = t + i * 256;
    if (idx < 2176) {
      int row = idx >> 6;
      int c4  = (idx & 63) << 2;
      int gy  = y0 - 1 + row;
      ushort4 vv = make_ushort4(0, 0, 0, 0);       // zero-pad y boundary
      if (gy >= 0 && gy < HH)
        vv = *(const ushort4*)(base + (size_t)gy * WW + c4);
      *(ushort4*)(&lds[row][c4]) = vv;
    }
  }

  float wv[9];
  #pragma unroll
  for (int i = 0; i < 9; ++i) wv[i] = w9[((size_t)qsel * CDIM + o) * 9 + i];
  float bo = bias[qsel * CDIM + o];
  __syncthreads();

  int w = t >> 6, lane = t & 63;
  int x0 = lane << 2;                       // 4 columns per lane
  float sumsq = 0.f;
  unsigned short* outbase = outp + ((size_t)z * CDIM + o) * NPIX;

  #pragma unroll
  for (int i = 0; i < 8; ++i) {
    int yo = w * 8 + i;                     // local output row (0..31)
    float a0 = bo, a1 = bo, a2 = bo, a3 = bo;
    #pragma unroll
    for (int dy = 0; dy < 3; ++dy) {
      ushort4 mv = *(const ushort4*)(&lds[yo + dy][x0]);   // ds_read_b64
      float v0 = b2f(mv.x), v1 = b2f(mv.y), v2 = b2f(mv.z), v3 = b2f(mv.w);
      float vl = __shfl_up(v3, 1, 64);   if (lane == 0)  vl = 0.f;  // x=-1
      float vr = __shfl_down(v0, 1, 64); if (lane == 63) vr = 0.f;  // x=256
      float w0 = wv[dy * 3 + 0], w1 = wv[dy * 3 + 1], w2 = wv[dy * 3 + 2];
      a0 += w0 * vl + w1 * v0 + w2 * v1;
      a1 += w0 * v0 + w1 * v1 + w2 * v2;
      a2 += w0 * v1 + w1 * v2 + w2 * v3;
      a3 += w0 * v2 + w1 * v3 + w2 * vr;
    }
    ushort4 ov;
    ov.x = f2b(a0); ov.y = f2b(a1); ov.z = f2b(a2); ov.w = f2b(a3);
    *(ushort4*)(outbase + (size_t)(y0 + yo) * WW + x0) = ov;    // 8B store
    if (ssqBase != nullptr) sumsq += a0 * a0 + a1 * a1 + a2 * a2 + a3 * a3;
  }

  if (ssqBase != nullptr) {                 // uniform per launch
    float* ssq = ssqBase + (size_t)(z >> 1) * 2 * CDIM + (z & 1) * CDIM;
    #pragma unroll
    for (int off = 32; off; off >>= 1) sumsq += __shfl_down(sumsq, off, 64);
    if (lane == 0) red[w] = sumsq;
    __syncthreads();
    if (t == 0) atomicAdd(&ssq[o], red[0] + red[1] + red[2] + red[3]);
  }
}

// ---------------- Gram: S[b][h][c][d] = sum_n q[...]*k[...]
// post layout: z = b*2 + {0:q, 1:k}. grid (128, HEADS, 2), chunk = 512.
__global__ __launch_bounds__(256)
void gram(const unsigned short* __restrict__ post,   // [4][192][N] bf16
          float* __restrict__ S)                     // [2][HEADS][32][32]
{
  int h = blockIdx.y, b = blockIdx.z;
  int t = threadIdx.x, wid = t >> 6, lane = t & 63;
  int r = lane & 15, quad = lane >> 4;
  int c0 = (wid >> 1) * 16, d0 = (wid & 1) * 16;
  size_t nb = (size_t)blockIdx.x * 512 + quad * 8;
  const unsigned short* qrow =
      post + ((size_t)(b * 2 + 0) * CDIM + h * 32 + c0 + r) * NPIX + nb;
  const unsigned short* krow =
      post + ((size_t)(b * 2 + 1) * CDIM + h * 32 + d0 + r) * NPIX + nb;
  f32x4 acc = (f32x4){0.f, 0.f, 0.f, 0.f};
  #pragma unroll
  for (int kk = 0; kk < 512; kk += 32) {
    bf16x8 af  = *(const bf16x8*)(qrow + kk);
    bf16x8 bfr = *(const bf16x8*)(krow + kk);
    acc = __builtin_amdgcn_mfma_f32_16x16x32_bf16(af, bfr, acc, 0, 0, 0);
  }
  float* Sp = S + ((size_t)b * HEADS + h) * 1024;
  #pragma unroll
  for (int i = 0; i < 4; ++i)
    atomicAdd(&Sp[(c0 + quad * 4 + i) * 32 + (d0 + r)], acc[i]);
}

// ---------------- scale by 1/(|q||k|)*temp, softmax over d (32-wide)
// grid (HEADS, 2)
__global__ void softmax_scale(const float* __restrict__ S,    // [2][HEADS][1024]
                              const float* __restrict__ ssq,  // [2][2][192]
                              const float* __restrict__ temp, // [HEADS]
                              float* __restrict__ P)          // [2][HEADS][1024]
{
  int h = blockIdx.x, b = blockIdx.y;
  int t = threadIdx.x;
  int c = t >> 5, d = t & 31;
  float nq = fmaxf(sqrtf(ssq[(size_t)b * 2 * CDIM + h * 32 + c]), 1e-12f);
  float nk = fmaxf(sqrtf(ssq[(size_t)b * 2 * CDIM + CDIM + h * 32 + d]), 1e-12f);
  float v = S[((size_t)b * HEADS + h) * 1024 + t] / (nq * nk) * temp[h];
  float m = v;
  for (int off = 16; off; off >>= 1) m = fmaxf(m, __shfl_xor(m, off, 32));
  float e = expf(v - m);
  float s = e;
  for (int off = 16; off; off >>= 1) s += __shfl_xor(s, off, 32);
  P[((size_t)b * HEADS + h) * 1024 + t] = e / s;
}

// ---------------- att[c,n] = (sum_d P[c,d]*v[d,n]) * sigmoid(gate[c,n])
// post2 layout: z = b*2 + {0:v, 1:gate}. grid (256, HEADS, 2).
__global__ __launch_bounds__(256)
void pv_gate(const unsigned short* __restrict__ post2, // [4][192][N] bf16
             const float* __restrict__ P,              // [2][HEADS][1024]
             unsigned short* __restrict__ attB)        // [2][192][N] bf16
{
  int h = blockIdx.y, b = blockIdx.z;
  size_t n = (size_t)blockIdx.x * 256 + threadIdx.x;
  const unsigned short* vb = post2 + ((size_t)(b * 2 + 0) * CDIM + h * 32) * NPIX + n;
  const unsigned short* gb = post2 + ((size_t)(b * 2 + 1) * CDIM + h * 32) * NPIX + n;
  const float* Pb = P + ((size_t)b * HEADS + h) * 1024;
  __shared__ float Ps[1024];
  for (int i = threadIdx.x; i < 1024; i += 256) Ps[i] = Pb[i];
  __syncthreads();
  float vr[32];
  #pragma unroll
  for (int d = 0; d < 32; ++d) vr[d] = b2f(vb[(size_t)d * NPIX]);
  unsigned short* outb = attB + ((size_t)b * CDIM + h * 32) * NPIX + n;
  #pragma unroll
  for (int c = 0; c < 32; ++c) {
    float a = 0.f;
    #pragma unroll
    for (int d = 0; d < 32; ++d) a += Ps[c * 32 + d] * vr[d];
    float gg = b2f(gb[(size_t)c * NPIX]);
    float sg = 1.f / (1.f + expf(-gg));
    outb[(size_t)c * NPIX] = f2b(a * sg);
  }
}

extern "C" void kernel_launch(void* const* d_in, const int* in_sizes, int n_in,
                              void* d_out, int out_size, void* d_ws, size_t ws_size,
                              hipStream_t stream)
{
  const float* x      = (const float*)d_in[0];
  const float* qkv_w  = (const float*)d_in[1];
  const float* qkv_b  = (const float*)d_in[2];
  const float* dw_w   = (const float*)d_in[3];
  const float* dw_b   = (const float*)d_in[4];
  const float* temp   = (const float*)d_in[5];
  const float* proj_w = (const float*)d_in[6];
  const float* proj_b = (const float*)d_in[7];
  float* out = (float*)d_out;

  char* ws = (char*)d_ws;
  const size_t qbytes = (size_t)CDIM * NPIX * 2;   // 25,165,824
  unsigned short* xbf   = (unsigned short*)ws;                  // 2 slots
  unsigned short* pre   = (unsigned short*)(ws + 2 * qbytes);   // 4 slots (also att)
  unsigned short* post  = (unsigned short*)(ws + 6 * qbytes);   // 4 slots: q,k
  unsigned short* post2 = (unsigned short*)(ws + 10 * qbytes);  // 4 slots: v,gate
  float* S   = (float*)(ws + 14 * qbytes);     // 2*6*1024
  float* ssq = S + 2 * HEADS * 1024;           // 2*2*192
  float* P   = ssq + 2 * 2 * CDIM;             // 2*6*1024
  const int nz = 2 * HEADS * 1024 + 2 * 2 * CDIM;   // S + ssq

  zero_init<<<(nz + 255) / 256, 256, 0, stream>>>(S, nz);
  x2bf<<<2048, 256, 0, stream>>>(x, xbf);

  // phase 1: q (quarter 0) + k (quarter 2), both batches. z = b*2 + {0:q,1:k}
  gemm_bias<false><<<dim3(3, 1024, 4), 256, 0, stream>>>(qkv_w, qkv_b, xbf, pre, 0, 2, 1);
  dwconv_ssq<<<dim3(CDIM * 8, 1, 4), 256, 0, stream>>>(pre, dw_w, dw_b, post, ssq, 0, 2);

  // phase 2: v (quarter 3) + gate (quarter 1). z = b*2 + {0:v,1:g}
  gemm_bias<false><<<dim3(3, 1024, 4), 256, 0, stream>>>(qkv_w, qkv_b, xbf, pre, 3, 1, 1);
  dwconv_ssq<<<dim3(CDIM * 8, 1, 4), 256, 0, stream>>>(pre, dw_w, dw_b, post2, nullptr, 3, 1);

  gram<<<dim3(128, HEADS, 2), 256, 0, stream>>>(post, S);
  softmax_scale<<<dim3(HEADS, 2), 1024, 0, stream>>>(S, ssq, temp, P);

  // att -> pre[0..1] (pre free after dwconv of phase 2)
  pv_gate<<<dim3(NPIX / 256, HEADS, 2), 256, 0, stream>>>(post2, P, pre);

  // proj: A fixed (qs0=qs1=0), B batch = z (bShift=0), fp32 out
  gemm_bias<true><<<dim3(3, 1024, 2), 256, 0, stream>>>(proj_w, proj_b, pre, out, 0, 0, 0);
}

// Round 3
// 574.454 us; speedup vs baseline: 3.2918x; 1.0725x over previous
//
#include <hip/hip_runtime.h>
#include <math.h>

// GatedMDTA: B=2, C=192, H=W=256, HEADS=6, hd=32, QC=768.
// Round 8: transpose-free GEMM. xT[b][n][200] bf16 (pre-transposed, padded
// rows) + wbf[5][192][200] bf16 (pre-converted weights) make BOTH GEMM tiles
// contiguous linear copies into LDS -> no bank conflicts (was 3.9e7), no f2b
// in staging, no scalar writes. MFMA operand roles swapped (A=pixels, B=W^T;
// both frags use the identical row=lane&15, k=quad*8+j addressing). m-loop
// inside block (6 m-tiles for qkv pair, 3 for proj) reuses the staged B-tile.
// pv_gate now writes attT n-major (64B/thread stores) feeding proj same path.
// dwconv / gram / softmax unchanged from round 7.
//
// ws layout: xT 52.43MB | wbf 0.38MB | pre 4q (=attT reuse) | post 4q |
//            post2 4q | S/ssq/P floats.  Total ~355MB < 402MB ws.

#define HEADS 6
#define CDIM 192
#define QCH 768
#define HH 256
#define WW 256
#define NPIX 65536
#define PADC 200   // padded channel row stride (ushorts)

typedef __bf16 bf16x8 __attribute__((ext_vector_type(8)));
typedef float f32x4 __attribute__((ext_vector_type(4)));
typedef unsigned short u16x8 __attribute__((ext_vector_type(8)));

__device__ __forceinline__ float b2f(unsigned short u) {
  union { unsigned int i; float f; } x; x.i = ((unsigned int)u) << 16; return x.f;
}
__device__ __forceinline__ unsigned short f2b(float f) {
  union { float f; unsigned int i; } x; x.f = f;
  unsigned int lsb = (x.i >> 16) & 1u;
  x.i += 0x7fffu + lsb;           // round-to-nearest-even
  return (unsigned short)(x.i >> 16);
}

// ---------------- zero-init small fp32 scratch
__global__ void zero_init(float* __restrict__ p, int n) {
  int i = blockIdx.x * 256 + threadIdx.x;
  if (i < n) p[i] = 0.f;
}

// ---------------- weights fp32 -> bf16, padded rows [5][192][200]
// q 0..3 = qkv quarters, q 4 = proj.
__global__ __launch_bounds__(256)
void w2bf(const float* __restrict__ qkv_w, const float* __restrict__ proj_w,
          unsigned short* __restrict__ wbf) {
  int id = blockIdx.x * 256 + threadIdx.x;      // < 5*192*192 = 184320
  if (id >= 5 * 192 * 192) return;
  int k = id % 192;
  int m = (id / 192) % 192;
  int q = id / (192 * 192);
  float v = (q < 4) ? qkv_w[(size_t)(q * 192 + m) * 192 + k]
                    : proj_w[(size_t)m * 192 + k];
  wbf[((size_t)q * 192 + m) * PADC + k] = f2b(v);
}

// ---------------- x fp32 [b][c][n] -> xT bf16 [b][n][PADC]  (transpose)
// block = (n-tile of 64, b). LDS tile [64][200] ushort.
__global__ __launch_bounds__(256)
void x2t(const float* __restrict__ x, unsigned short* __restrict__ xT) {
  __shared__ unsigned short tile[64 * PADC];
  int t = threadIdx.x;
  int n0 = blockIdx.x * 64;
  int b = blockIdx.y;
  // read 192c x 64n fp32 (coalesced rows), write transposed into LDS
  #pragma unroll
  for (int i = 0; i < 12; ++i) {
    int idx = t + i * 256;                 // 0..3071 float4 chunks
    int c = idx >> 4;                      // 0..191
    int nn4 = (idx & 15) << 2;             // 0..60
    float4 v = *(const float4*)(x + ((size_t)b * CDIM + c) * NPIX + n0 + nn4);
    tile[(nn4 + 0) * PADC + c] = f2b(v.x);
    tile[(nn4 + 1) * PADC + c] = f2b(v.y);
    tile[(nn4 + 2) * PADC + c] = f2b(v.z);
    tile[(nn4 + 3) * PADC + c] = f2b(v.w);
  }
  __syncthreads();
  // write 64 rows x 192 ushorts (pads left unwritten; never read)
  #pragma unroll
  for (int i = 0; i < 6; ++i) {
    int idx = t + i * 256;                 // 0..1535 : 64 rows x 24 chunks
    int row = idx / 24;
    int c8 = (idx % 24) * 8;
    *(u16x8*)(xT + ((size_t)b * NPIX + n0 + row) * PADC + c8) =
        *(const u16x8*)(tile + row * PADC + c8);
  }
}

// ---------------- GEMM: outT-free, transpose-free.
// D[n-tile][m-tile] = xT[n][c] * W^T[c][m]; A-op = xT frag, B-op = W frag.
// NMT m-tiles looped per block (6 = two quarters for qkv pair, 3 = proj).
// Output written c-major: out[m][n] (bf16 quarters or fp32 final).
template <int NMT, bool OUT_F32>
__global__ __launch_bounds__(256)
void gemm_t(const unsigned short* __restrict__ wq0,   // [192][PADC] bf16
            const unsigned short* __restrict__ wq1,   // [192][PADC] bf16
            const float* __restrict__ bias0,          // [192]
            const float* __restrict__ bias1,          // [192]
            const unsigned short* __restrict__ Bsrc,  // [2][NPIX][PADC] bf16
            void* __restrict__ outB)                  // bf16 [4][192][N] / f32 [2][192][N]
{
  __shared__ unsigned short a_lds[64 * PADC];   // W tile (64 m x 192 k)
  __shared__ unsigned short b_lds[64 * PADC];   // xT tile (64 n x 192 c)
  int t = threadIdx.x;
  int n0 = blockIdx.x * 64;
  int b = blockIdx.y;

  // stage B tile: one contiguous 64*PADC region, linear 16B copies
  const unsigned short* Bs = Bsrc + ((size_t)b * NPIX + n0) * PADC;
  #pragma unroll
  for (int i = 0; i < 6; ++i) {
    int idx = t + i * 256;
    *(u16x8*)(b_lds + idx * 8) = *(const u16x8*)(Bs + (size_t)idx * 8);
  }
  if (t < 64) {
    int idx = 1536 + t;
    *(u16x8*)(b_lds + idx * 8) = *(const u16x8*)(Bs + (size_t)idx * 8);
  }

  int wid = t >> 6, lane = t & 63;
  int r = lane & 15, quad = lane >> 4;

  #pragma unroll
  for (int mt = 0; mt < NMT; ++mt) {
    int half = mt / 3;                  // which quarter (0: wq0, 1: wq1)
    int mrow = (mt % 3) * 64;           // m-tile base within the 192-row quarter
    const unsigned short* wq = (half ? wq1 : wq0) + (size_t)mrow * PADC;

    __syncthreads();                    // prev iter's a_lds reads done (+ b stage)
    #pragma unroll
    for (int i = 0; i < 6; ++i) {
      int idx = t + i * 256;
      *(u16x8*)(a_lds + idx * 8) = *(const u16x8*)(wq + (size_t)idx * 8);
    }
    if (t < 64) {
      int idx = 1536 + t;
      *(u16x8*)(a_lds + idx * 8) = *(const u16x8*)(wq + (size_t)idx * 8);
    }
    __syncthreads();

    f32x4 acc[4];
    #pragma unroll
    for (int nt = 0; nt < 4; ++nt) acc[nt] = (f32x4){0.f, 0.f, 0.f, 0.f};

    #pragma unroll
    for (int kk = 0; kk < 192; kk += 32) {
      bf16x8 xf = *(const bf16x8*)(b_lds + (wid * 16 + r) * PADC + kk + quad * 8);
      #pragma unroll
      for (int nt = 0; nt < 4; ++nt) {
        bf16x8 wf = *(const bf16x8*)(a_lds + (nt * 16 + r) * PADC + kk + quad * 8);
        acc[nt] = __builtin_amdgcn_mfma_f32_16x16x32_bf16(xf, wf, acc[nt], 0, 0, 0);
      }
    }

    // D: row(M=n) = quad*4+i, col(N=m) = lane&15. Per lane: 4 consecutive n.
    const float* bp = half ? bias1 : bias0;
    size_t n = (size_t)n0 + wid * 16 + quad * 4;
    if (OUT_F32) {
      float* op = (float*)outB + (size_t)b * CDIM * NPIX;
      #pragma unroll
      for (int nt = 0; nt < 4; ++nt) {
        int m = mrow + nt * 16 + r;
        float bb = bp[m];
        float4 vv;
        vv.x = acc[nt][0] + bb; vv.y = acc[nt][1] + bb;
        vv.z = acc[nt][2] + bb; vv.w = acc[nt][3] + bb;
        *(float4*)(op + (size_t)m * NPIX + n) = vv;
      }
    } else {
      unsigned short* op = (unsigned short*)outB +
                           (size_t)(b * 2 + half) * CDIM * NPIX;
      #pragma unroll
      for (int nt = 0; nt < 4; ++nt) {
        int m = mrow + nt * 16 + r;
        float bb = bp[m];
        ushort4 uu;
        uu.x = f2b(acc[nt][0] + bb); uu.y = f2b(acc[nt][1] + bb);
        uu.z = f2b(acc[nt][2] + bb); uu.w = f2b(acc[nt][3] + bb);
        *(ushort4*)(op + (size_t)m * NPIX + n) = uu;
      }
    }
  }
}

// ---------------- 3x3 depthwise conv + bias; optional fused per-channel ssq.
// block = (channel o, 32-row group); z = quarter-slot (b*2 + which). (unchanged)
__global__ __launch_bounds__(256)
void dwconv_ssq(const unsigned short* __restrict__ in,   // [z][192][H][W] bf16
                const float* __restrict__ w9,            // [4][192][9] fp32
                const float* __restrict__ bias,          // [4][192] fp32
                unsigned short* __restrict__ outp,       // [z][192][H][W] bf16
                float* __restrict__ ssqBase,             // [2][2][192] or null
                int qs0, int qs1)
{
  __shared__ unsigned short lds[34][256];   // rows y0-1 .. y0+32
  __shared__ float red[4];
  int t = threadIdx.x;
  int z = blockIdx.z;
  int qsel = (z & 1) ? qs1 : qs0;
  int o  = blockIdx.x >> 3;                 // channel 0..191
  int ry = blockIdx.x & 7;                  // row group 0..7
  int y0 = ry << 5;                         // first output row

  const unsigned short* base = in + ((size_t)z * CDIM + o) * NPIX;
  #pragma unroll
  for (int i = 0; i < 9; ++i) {
    int idx = t + i * 256;
    if (idx < 2176) {
      int row = idx >> 6;
      int c4  = (idx & 63) << 2;
      int gy  = y0 - 1 + row;
      ushort4 vv = make_ushort4(0, 0, 0, 0);       // zero-pad y boundary
      if (gy >= 0 && gy < HH)
        vv = *(const ushort4*)(base + (size_t)gy * WW + c4);
      *(ushort4*)(&lds[row][c4]) = vv;
    }
  }

  float wv[9];
  #pragma unroll
  for (int i = 0; i < 9; ++i) wv[i] = w9[((size_t)qsel * CDIM + o) * 9 + i];
  float bo = bias[qsel * CDIM + o];
  __syncthreads();

  int w = t >> 6, lane = t & 63;
  int x0 = lane << 2;                       // 4 columns per lane
  float sumsq = 0.f;
  unsigned short* outbase = outp + ((size_t)z * CDIM + o) * NPIX;

  #pragma unroll
  for (int i = 0; i < 8; ++i) {
    int yo = w * 8 + i;                     // local output row (0..31)
    float a0 = bo, a1 = bo, a2 = bo, a3 = bo;
    #pragma unroll
    for (int dy = 0; dy < 3; ++dy) {
      ushort4 mv = *(const ushort4*)(&lds[yo + dy][x0]);   // ds_read_b64
      float v0 = b2f(mv.x), v1 = b2f(mv.y), v2 = b2f(mv.z), v3 = b2f(mv.w);
      float vl = __shfl_up(v3, 1, 64);   if (lane == 0)  vl = 0.f;  // x=-1
      float vr = __shfl_down(v0, 1, 64); if (lane == 63) vr = 0.f;  // x=256
      float w0 = wv[dy * 3 + 0], w1 = wv[dy * 3 + 1], w2 = wv[dy * 3 + 2];
      a0 += w0 * vl + w1 * v0 + w2 * v1;
      a1 += w0 * v0 + w1 * v1 + w2 * v2;
      a2 += w0 * v1 + w1 * v2 + w2 * v3;
      a3 += w0 * v2 + w1 * v3 + w2 * vr;
    }
    ushort4 ov;
    ov.x = f2b(a0); ov.y = f2b(a1); ov.z = f2b(a2); ov.w = f2b(a3);
    *(ushort4*)(outbase + (size_t)(y0 + yo) * WW + x0) = ov;    // 8B store
    if (ssqBase != nullptr) sumsq += a0 * a0 + a1 * a1 + a2 * a2 + a3 * a3;
  }

  if (ssqBase != nullptr) {                 // uniform per launch
    float* ssq = ssqBase + (size_t)(z >> 1) * 2 * CDIM + (z & 1) * CDIM;
    #pragma unroll
    for (int off = 32; off; off >>= 1) sumsq += __shfl_down(sumsq, off, 64);
    if (lane == 0) red[w] = sumsq;
    __syncthreads();
    if (t == 0) atomicAdd(&ssq[o], red[0] + red[1] + red[2] + red[3]);
  }
}

// ---------------- Gram: S[b][h][c][d] = sum_n q[...]*k[...]  (unchanged)
__global__ __launch_bounds__(256)
void gram(const unsigned short* __restrict__ post,   // [4][192][N] bf16
          float* __restrict__ S)                     // [2][HEADS][32][32]
{
  int h = blockIdx.y, b = blockIdx.z;
  int t = threadIdx.x, wid = t >> 6, lane = t & 63;
  int r = lane & 15, quad = lane >> 4;
  int c0 = (wid >> 1) * 16, d0 = (wid & 1) * 16;
  size_t nb = (size_t)blockIdx.x * 512 + quad * 8;
  const unsigned short* qrow =
      post + ((size_t)(b * 2 + 0) * CDIM + h * 32 + c0 + r) * NPIX + nb;
  const unsigned short* krow =
      post + ((size_t)(b * 2 + 1) * CDIM + h * 32 + d0 + r) * NPIX + nb;
  f32x4 acc = (f32x4){0.f, 0.f, 0.f, 0.f};
  #pragma unroll
  for (int kk = 0; kk < 512; kk += 32) {
    bf16x8 af  = *(const bf16x8*)(qrow + kk);
    bf16x8 bfr = *(const bf16x8*)(krow + kk);
    acc = __builtin_amdgcn_mfma_f32_16x16x32_bf16(af, bfr, acc, 0, 0, 0);
  }
  float* Sp = S + ((size_t)b * HEADS + h) * 1024;
  #pragma unroll
  for (int i = 0; i < 4; ++i)
    atomicAdd(&Sp[(c0 + quad * 4 + i) * 32 + (d0 + r)], acc[i]);
}

// ---------------- scale + softmax (unchanged)
__global__ void softmax_scale(const float* __restrict__ S,    // [2][HEADS][1024]
                              const float* __restrict__ ssq,  // [2][2][192]
                              const float* __restrict__ temp, // [HEADS]
                              float* __restrict__ P)          // [2][HEADS][1024]
{
  int h = blockIdx.x, b = blockIdx.y;
  int t = threadIdx.x;
  int c = t >> 5, d = t & 31;
  float nq = fmaxf(sqrtf(ssq[(size_t)b * 2 * CDIM + h * 32 + c]), 1e-12f);
  float nk = fmaxf(sqrtf(ssq[(size_t)b * 2 * CDIM + CDIM + h * 32 + d]), 1e-12f);
  float v = S[((size_t)b * HEADS + h) * 1024 + t] / (nq * nk) * temp[h];
  float m = v;
  for (int off = 16; off; off >>= 1) m = fmaxf(m, __shfl_xor(m, off, 32));
  float e = expf(v - m);
  float s = e;
  for (int off = 16; off; off >>= 1) s += __shfl_xor(s, off, 32);
  P[((size_t)b * HEADS + h) * 1024 + t] = e / s;
}

// ---------------- att = (P @ v) * sigmoid(gate); writes attT n-major [b][n][PADC]
__global__ __launch_bounds__(256)
void pv_gate(const unsigned short* __restrict__ post2, // [4][192][N] bf16
             const float* __restrict__ P,              // [2][HEADS][1024]
             unsigned short* __restrict__ attT)        // [2][NPIX][PADC] bf16
{
  int h = blockIdx.y, b = blockIdx.z;
  size_t n = (size_t)blockIdx.x * 256 + threadIdx.x;
  const unsigned short* vb = post2 + ((size_t)(b * 2 + 0) * CDIM + h * 32) * NPIX + n;
  const unsigned short* gb = post2 + ((size_t)(b * 2 + 1) * CDIM + h * 32) * NPIX + n;
  const float* Pb = P + ((size_t)b * HEADS + h) * 1024;
  __shared__ float Ps[1024];
  for (int i = threadIdx.x; i < 1024; i += 256) Ps[i] = Pb[i];
  __syncthreads();
  float vr[32];
  #pragma unroll
  for (int d = 0; d < 32; ++d) vr[d] = b2f(vb[(size_t)d * NPIX]);
  unsigned short ub[32];
  #pragma unroll
  for (int c = 0; c < 32; ++c) {
    float a = 0.f;
    #pragma unroll
    for (int d = 0; d < 32; ++d) a += Ps[c * 32 + d] * vr[d];
    float gg = b2f(gb[(size_t)c * NPIX]);
    float sg = 1.f / (1.f + expf(-gg));
    ub[c] = f2b(a * sg);
  }
  unsigned short* op = attT + ((size_t)b * NPIX + n) * PADC + h * 32;
  #pragma unroll
  for (int c8 = 0; c8 < 4; ++c8)
    *(u16x8*)(op + c8 * 8) = *(const u16x8*)(ub + c8 * 8);
}

extern "C" void kernel_launch(void* const* d_in, const int* in_sizes, int n_in,
                              void* d_out, int out_size, void* d_ws, size_t ws_size,
                              hipStream_t stream)
{
  const float* x      = (const float*)d_in[0];
  const float* qkv_w  = (const float*)d_in[1];
  const float* qkv_b  = (const float*)d_in[2];
  const float* dw_w   = (const float*)d_in[3];
  const float* dw_b   = (const float*)d_in[4];
  const float* temp   = (const float*)d_in[5];
  const float* proj_w = (const float*)d_in[6];
  const float* proj_b = (const float*)d_in[7];
  float* out = (float*)d_out;

  char* ws = (char*)d_ws;
  const size_t qbytes  = (size_t)CDIM * NPIX * 2;            // 25,165,824
  const size_t xTbytes = (size_t)2 * NPIX * PADC * 2;        // 52,428,800
  const size_t wbytes  = (size_t)5 * 192 * PADC * 2;         // 384,000
  unsigned short* xT    = (unsigned short*)ws;
  unsigned short* wbf   = (unsigned short*)(ws + xTbytes);
  unsigned short* pre   = (unsigned short*)(ws + xTbytes + wbytes);          // 4 slots
  unsigned short* post  = (unsigned short*)(ws + xTbytes + wbytes + 4 * qbytes);
  unsigned short* post2 = (unsigned short*)(ws + xTbytes + wbytes + 8 * qbytes);
  unsigned short* attT  = pre;                // reuse (pre dead after dwconv2)
  float* S   = (float*)(ws + xTbytes + wbytes + 12 * qbytes);
  float* ssq = S + 2 * HEADS * 1024;
  float* P   = ssq + 2 * 2 * CDIM;
  const int nz = 2 * HEADS * 1024 + 2 * 2 * CDIM;

  zero_init<<<(nz + 255) / 256, 256, 0, stream>>>(S, nz);
  w2bf<<<(5 * 192 * 192 + 255) / 256, 256, 0, stream>>>(qkv_w, proj_w, wbf);
  x2t<<<dim3(NPIX / 64, 2), 256, 0, stream>>>(x, xT);

  const unsigned short* wq = wbf;                      // quarter stride 192*PADC
  const size_t wqs = (size_t)192 * PADC;

  // phase 1: q (quarter 0) + k (quarter 2), both batches -> pre slots b*2+{0,1}
  gemm_t<6, false><<<dim3(NPIX / 64, 2), 256, 0, stream>>>(
      wq + 0 * wqs, wq + 2 * wqs, qkv_b + 0 * CDIM, qkv_b + 2 * CDIM, xT, pre);
  dwconv_ssq<<<dim3(CDIM * 8, 1, 4), 256, 0, stream>>>(pre, dw_w, dw_b, post, ssq, 0, 2);

  // phase 2: v (quarter 3) + gate (quarter 1) -> pre slots b*2+{0,1}
  gemm_t<6, false><<<dim3(NPIX / 64, 2), 256, 0, stream>>>(
      wq + 3 * wqs, wq + 1 * wqs, qkv_b + 3 * CDIM, qkv_b + 1 * CDIM, xT, pre);
  dwconv_ssq<<<dim3(CDIM * 8, 1, 4), 256, 0, stream>>>(pre, dw_w, dw_b, post2, nullptr, 3, 1);

  gram<<<dim3(128, HEADS, 2), 256, 0, stream>>>(post, S);
  softmax_scale<<<dim3(HEADS, 2), 1024, 0, stream>>>(S, ssq, temp, P);

  // att -> attT (n-major, overlays pre)
  pv_gate<<<dim3(NPIX / 256, HEADS, 2), 256, 0, stream>>>(post2, P, attT);

  // proj: 3 m-tiles, fp32 out c-major
  gemm_t<3, true><<<dim3(NPIX / 64, 2), 256, 0, stream>>>(
      wq + 4 * wqs, wq + 4 * wqs, proj_b, proj_b, attT, out);
}

// Round 4
// 531.645 us; speedup vs baseline: 3.5569x; 1.0805x over previous
//
#include <hip/hip_runtime.h>
#include <math.h>

// GatedMDTA: B=2, C=192, H=W=256, HEADS=6, hd=32, QC=768.
// Round 9: pv_gate rewrite. Round-8 profile: pv_gate 106us, MfmaUtil 0,
// VALUBusy 48%, WRITE 70MB (ideal 26). Cause 1: 1024 broadcast ds_read_b32
// per thread for P (LDS-pipe bound, ~285K cyc/CU = matches 106us). Cause 2:
// attT stores 64B at 400B thread stride (2.7x write amplification).
// Fix: P read directly from global with block-uniform float4 indices
// (compiler scalar-promotes to s_load; P is const __restrict__), no LDS;
// attT layout -> [b][h][n][32] so each thread's 32 outputs are one aligned
// contiguous 64B store. proj GEMM gains BL=1 staging variant for that layout.
// Everything else identical to round 8.
//
// ws layout: xT 52.43MB | wbf 0.38MB | pre 4q (attT overlays) | post 4q |
//            post2 4q | S/ssq/P floats.  Total ~355MB < 402MB ws.

#define HEADS 6
#define CDIM 192
#define QCH 768
#define HH 256
#define WW 256
#define NPIX 65536
#define PADC 200   // padded channel row stride (ushorts)

typedef __bf16 bf16x8 __attribute__((ext_vector_type(8)));
typedef float f32x4 __attribute__((ext_vector_type(4)));
typedef unsigned short u16x8 __attribute__((ext_vector_type(8)));

__device__ __forceinline__ float b2f(unsigned short u) {
  union { unsigned int i; float f; } x; x.i = ((unsigned int)u) << 16; return x.f;
}
__device__ __forceinline__ unsigned short f2b(float f) {
  union { float f; unsigned int i; } x; x.f = f;
  unsigned int lsb = (x.i >> 16) & 1u;
  x.i += 0x7fffu + lsb;           // round-to-nearest-even
  return (unsigned short)(x.i >> 16);
}

// ---------------- zero-init small fp32 scratch
__global__ void zero_init(float* __restrict__ p, int n) {
  int i = blockIdx.x * 256 + threadIdx.x;
  if (i < n) p[i] = 0.f;
}

// ---------------- weights fp32 -> bf16, padded rows [5][192][200]
// q 0..3 = qkv quarters, q 4 = proj.
__global__ __launch_bounds__(256)
void w2bf(const float* __restrict__ qkv_w, const float* __restrict__ proj_w,
          unsigned short* __restrict__ wbf) {
  int id = blockIdx.x * 256 + threadIdx.x;      // < 5*192*192 = 184320
  if (id >= 5 * 192 * 192) return;
  int k = id % 192;
  int m = (id / 192) % 192;
  int q = id / (192 * 192);
  float v = (q < 4) ? qkv_w[(size_t)(q * 192 + m) * 192 + k]
                    : proj_w[(size_t)m * 192 + k];
  wbf[((size_t)q * 192 + m) * PADC + k] = f2b(v);
}

// ---------------- x fp32 [b][c][n] -> xT bf16 [b][n][PADC]  (transpose)
__global__ __launch_bounds__(256)
void x2t(const float* __restrict__ x, unsigned short* __restrict__ xT) {
  __shared__ unsigned short tile[64 * PADC];
  int t = threadIdx.x;
  int n0 = blockIdx.x * 64;
  int b = blockIdx.y;
  #pragma unroll
  for (int i = 0; i < 12; ++i) {
    int idx = t + i * 256;                 // 0..3071 float4 chunks
    int c = idx >> 4;                      // 0..191
    int nn4 = (idx & 15) << 2;             // 0..60
    float4 v = *(const float4*)(x + ((size_t)b * CDIM + c) * NPIX + n0 + nn4);
    tile[(nn4 + 0) * PADC + c] = f2b(v.x);
    tile[(nn4 + 1) * PADC + c] = f2b(v.y);
    tile[(nn4 + 2) * PADC + c] = f2b(v.z);
    tile[(nn4 + 3) * PADC + c] = f2b(v.w);
  }
  __syncthreads();
  #pragma unroll
  for (int i = 0; i < 6; ++i) {
    int idx = t + i * 256;                 // 0..1535 : 64 rows x 24 chunks
    int row = idx / 24;
    int c8 = (idx % 24) * 8;
    *(u16x8*)(xT + ((size_t)b * NPIX + n0 + row) * PADC + c8) =
        *(const u16x8*)(tile + row * PADC + c8);
  }
}

// ---------------- GEMM, transpose-free. A-op = pixels (xT/attT), B-op = W.
// BL=0: Bsrc is [b][n][PADC].  BL=1: Bsrc is [b][h][n][32] (attT head-chunks).
// NMT m-tiles looped per block. Output c-major: bf16 quarters or fp32 final.
template <int NMT, bool OUT_F32, int BL>
__global__ __launch_bounds__(256)
void gemm_t(const unsigned short* __restrict__ wq0,   // [192][PADC] bf16
            const unsigned short* __restrict__ wq1,   // [192][PADC] bf16
            const float* __restrict__ bias0,          // [192]
            const float* __restrict__ bias1,          // [192]
            const unsigned short* __restrict__ Bsrc,  // see BL
            void* __restrict__ outB)
{
  __shared__ unsigned short a_lds[64 * PADC];   // W tile (64 m x 192 k)
  __shared__ unsigned short b_lds[64 * PADC];   // pixel tile (64 n x 192 c)
  int t = threadIdx.x;
  int n0 = blockIdx.x * 64;
  int b = blockIdx.y;

  if (BL == 0) {
    // one contiguous 64*PADC region, linear 16B copies
    const unsigned short* Bs = Bsrc + ((size_t)b * NPIX + n0) * PADC;
    #pragma unroll
    for (int i = 0; i < 6; ++i) {
      int idx = t + i * 256;
      *(u16x8*)(b_lds + idx * 8) = *(const u16x8*)(Bs + (size_t)idx * 8);
    }
    if (t < 64) {
      int idx = 1536 + t;
      *(u16x8*)(b_lds + idx * 8) = *(const u16x8*)(Bs + (size_t)idx * 8);
    }
  } else {
    // 6 head-chunks, each row 64B contiguous; 4 lanes per 64B segment
    const unsigned short* Bs = Bsrc + (size_t)b * HEADS * NPIX * 32;
    #pragma unroll
    for (int i = 0; i < 6; ++i) {
      int idx = t + i * 256;               // 0..1535
      int row = idx / 24, cp = idx % 24;   // cp = 8-elem chunk within 192
      int h = cp >> 2, d8 = cp & 3;
      *(u16x8*)(b_lds + row * PADC + cp * 8) =
          *(const u16x8*)(Bs + ((size_t)h * NPIX + n0 + row) * 32 + d8 * 8);
    }
  }

  int wid = t >> 6, lane = t & 63;
  int r = lane & 15, quad = lane >> 4;

  #pragma unroll
  for (int mt = 0; mt < NMT; ++mt) {
    int half = mt / 3;                  // which quarter (0: wq0, 1: wq1)
    int mrow = (mt % 3) * 64;           // m-tile base within the 192-row quarter
    const unsigned short* wq = (half ? wq1 : wq0) + (size_t)mrow * PADC;

    __syncthreads();                    // prev iter's a_lds reads done (+ b stage)
    #pragma unroll
    for (int i = 0; i < 6; ++i) {
      int idx = t + i * 256;
      *(u16x8*)(a_lds + idx * 8) = *(const u16x8*)(wq + (size_t)idx * 8);
    }
    if (t < 64) {
      int idx = 1536 + t;
      *(u16x8*)(a_lds + idx * 8) = *(const u16x8*)(wq + (size_t)idx * 8);
    }
    __syncthreads();

    f32x4 acc[4];
    #pragma unroll
    for (int nt = 0; nt < 4; ++nt) acc[nt] = (f32x4){0.f, 0.f, 0.f, 0.f};

    #pragma unroll
    for (int kk = 0; kk < 192; kk += 32) {
      bf16x8 xf = *(const bf16x8*)(b_lds + (wid * 16 + r) * PADC + kk + quad * 8);
      #pragma unroll
      for (int nt = 0; nt < 4; ++nt) {
        bf16x8 wf = *(const bf16x8*)(a_lds + (nt * 16 + r) * PADC + kk + quad * 8);
        acc[nt] = __builtin_amdgcn_mfma_f32_16x16x32_bf16(xf, wf, acc[nt], 0, 0, 0);
      }
    }

    // D: row(M=n) = quad*4+i, col(N=m) = lane&15. Per lane: 4 consecutive n.
    const float* bp = half ? bias1 : bias0;
    size_t n = (size_t)n0 + wid * 16 + quad * 4;
    if (OUT_F32) {
      float* op = (float*)outB + (size_t)b * CDIM * NPIX;
      #pragma unroll
      for (int nt = 0; nt < 4; ++nt) {
        int m = mrow + nt * 16 + r;
        float bb = bp[m];
        float4 vv;
        vv.x = acc[nt][0] + bb; vv.y = acc[nt][1] + bb;
        vv.z = acc[nt][2] + bb; vv.w = acc[nt][3] + bb;
        *(float4*)(op + (size_t)m * NPIX + n) = vv;
      }
    } else {
      unsigned short* op = (unsigned short*)outB +
                           (size_t)(b * 2 + half) * CDIM * NPIX;
      #pragma unroll
      for (int nt = 0; nt < 4; ++nt) {
        int m = mrow + nt * 16 + r;
        float bb = bp[m];
        ushort4 uu;
        uu.x = f2b(acc[nt][0] + bb); uu.y = f2b(acc[nt][1] + bb);
        uu.z = f2b(acc[nt][2] + bb); uu.w = f2b(acc[nt][3] + bb);
        *(ushort4*)(op + (size_t)m * NPIX + n) = uu;
      }
    }
  }
}

// ---------------- 3x3 depthwise conv + bias; optional fused per-channel ssq.
__global__ __launch_bounds__(256)
void dwconv_ssq(const unsigned short* __restrict__ in,   // [z][192][H][W] bf16
                const float* __restrict__ w9,            // [4][192][9] fp32
                const float* __restrict__ bias,          // [4][192] fp32
                unsigned short* __restrict__ outp,       // [z][192][H][W] bf16
                float* __restrict__ ssqBase,             // [2][2][192] or null
                int qs0, int qs1)
{
  __shared__ unsigned short lds[34][256];   // rows y0-1 .. y0+32
  __shared__ float red[4];
  int t = threadIdx.x;
  int z = blockIdx.z;
  int qsel = (z & 1) ? qs1 : qs0;
  int o  = blockIdx.x >> 3;                 // channel 0..191
  int ry = blockIdx.x & 7;                  // row group 0..7
  int y0 = ry << 5;                         // first output row

  const unsigned short* base = in + ((size_t)z * CDIM + o) * NPIX;
  #pragma unroll
  for (int i = 0; i < 9; ++i) {
    int idx = t + i * 256;
    if (idx < 2176) {
      int row = idx >> 6;
      int c4  = (idx & 63) << 2;
      int gy  = y0 - 1 + row;
      ushort4 vv = make_ushort4(0, 0, 0, 0);       // zero-pad y boundary
      if (gy >= 0 && gy < HH)
        vv = *(const ushort4*)(base + (size_t)gy * WW + c4);
      *(ushort4*)(&lds[row][c4]) = vv;
    }
  }

  float wv[9];
  #pragma unroll
  for (int i = 0; i < 9; ++i) wv[i] = w9[((size_t)qsel * CDIM + o) * 9 + i];
  float bo = bias[qsel * CDIM + o];
  __syncthreads();

  int w = t >> 6, lane = t & 63;
  int x0 = lane << 2;                       // 4 columns per lane
  float sumsq = 0.f;
  unsigned short* outbase = outp + ((size_t)z * CDIM + o) * NPIX;

  #pragma unroll
  for (int i = 0; i < 8; ++i) {
    int yo = w * 8 + i;                     // local output row (0..31)
    float a0 = bo, a1 = bo, a2 = bo, a3 = bo;
    #pragma unroll
    for (int dy = 0; dy < 3; ++dy) {
      ushort4 mv = *(const ushort4*)(&lds[yo + dy][x0]);   // ds_read_b64
      float v0 = b2f(mv.x), v1 = b2f(mv.y), v2 = b2f(mv.z), v3 = b2f(mv.w);
      float vl = __shfl_up(v3, 1, 64);   if (lane == 0)  vl = 0.f;  // x=-1
      float vr = __shfl_down(v0, 1, 64); if (lane == 63) vr = 0.f;  // x=256
      float w0 = wv[dy * 3 + 0], w1 = wv[dy * 3 + 1], w2 = wv[dy * 3 + 2];
      a0 += w0 * vl + w1 * v0 + w2 * v1;
      a1 += w0 * v0 + w1 * v1 + w2 * v2;
      a2 += w0 * v1 + w1 * v2 + w2 * v3;
      a3 += w0 * v2 + w1 * v3 + w2 * vr;
    }
    ushort4 ov;
    ov.x = f2b(a0); ov.y = f2b(a1); ov.z = f2b(a2); ov.w = f2b(a3);
    *(ushort4*)(outbase + (size_t)(y0 + yo) * WW + x0) = ov;    // 8B store
    if (ssqBase != nullptr) sumsq += a0 * a0 + a1 * a1 + a2 * a2 + a3 * a3;
  }

  if (ssqBase != nullptr) {                 // uniform per launch
    float* ssq = ssqBase + (size_t)(z >> 1) * 2 * CDIM + (z & 1) * CDIM;
    #pragma unroll
    for (int off = 32; off; off >>= 1) sumsq += __shfl_down(sumsq, off, 64);
    if (lane == 0) red[w] = sumsq;
    __syncthreads();
    if (t == 0) atomicAdd(&ssq[o], red[0] + red[1] + red[2] + red[3]);
  }
}

// ---------------- Gram: S[b][h][c][d] = sum_n q[...]*k[...]  (unchanged)
__global__ __launch_bounds__(256)
void gram(const unsigned short* __restrict__ post,   // [4][192][N] bf16
          float* __restrict__ S)                     // [2][HEADS][32][32]
{
  int h = blockIdx.y, b = blockIdx.z;
  int t = threadIdx.x, wid = t >> 6, lane = t & 63;
  int r = lane & 15, quad = lane >> 4;
  int c0 = (wid >> 1) * 16, d0 = (wid & 1) * 16;
  size_t nb = (size_t)blockIdx.x * 512 + quad * 8;
  const unsigned short* qrow =
      post + ((size_t)(b * 2 + 0) * CDIM + h * 32 + c0 + r) * NPIX + nb;
  const unsigned short* krow =
      post + ((size_t)(b * 2 + 1) * CDIM + h * 32 + d0 + r) * NPIX + nb;
  f32x4 acc = (f32x4){0.f, 0.f, 0.f, 0.f};
  #pragma unroll
  for (int kk = 0; kk < 512; kk += 32) {
    bf16x8 af  = *(const bf16x8*)(qrow + kk);
    bf16x8 bfr = *(const bf16x8*)(krow + kk);
    acc = __builtin_amdgcn_mfma_f32_16x16x32_bf16(af, bfr, acc, 0, 0, 0);
  }
  float* Sp = S + ((size_t)b * HEADS + h) * 1024;
  #pragma unroll
  for (int i = 0; i < 4; ++i)
    atomicAdd(&Sp[(c0 + quad * 4 + i) * 32 + (d0 + r)], acc[i]);
}

// ---------------- scale + softmax (unchanged)
__global__ void softmax_scale(const float* __restrict__ S,    // [2][HEADS][1024]
                              const float* __restrict__ ssq,  // [2][2][192]
                              const float* __restrict__ temp, // [HEADS]
                              float* __restrict__ P)          // [2][HEADS][1024]
{
  int h = blockIdx.x, b = blockIdx.y;
  int t = threadIdx.x;
  int c = t >> 5, d = t & 31;
  float nq = fmaxf(sqrtf(ssq[(size_t)b * 2 * CDIM + h * 32 + c]), 1e-12f);
  float nk = fmaxf(sqrtf(ssq[(size_t)b * 2 * CDIM + CDIM + h * 32 + d]), 1e-12f);
  float v = S[((size_t)b * HEADS + h) * 1024 + t] / (nq * nk) * temp[h];
  float m = v;
  for (int off = 16; off; off >>= 1) m = fmaxf(m, __shfl_xor(m, off, 32));
  float e = expf(v - m);
  float s = e;
  for (int off = 16; off; off >>= 1) s += __shfl_xor(s, off, 32);
  P[((size_t)b * HEADS + h) * 1024 + t] = e / s;
}

// ---------------- att = (P @ v) * sigmoid(gate); writes attT [b][h][n][32]
// P read directly from global with block-uniform float4 indices (scalar-
// promotable: P is const __restrict__, index depends only on blockIdx +
// unrolled constants). No LDS. Store = one aligned contiguous 64B per thread.
__global__ __launch_bounds__(256)
void pv_gate(const unsigned short* __restrict__ post2, // [4][192][N] bf16
             const float* __restrict__ P,              // [2][HEADS][1024]
             unsigned short* __restrict__ attT)        // [2][HEADS][NPIX][32] bf16
{
  int h = blockIdx.y, b = blockIdx.z;
  size_t n = (size_t)blockIdx.x * 256 + threadIdx.x;
  const unsigned short* vb = post2 + ((size_t)(b * 2 + 0) * CDIM + h * 32) * NPIX + n;
  const unsigned short* gb = post2 + ((size_t)(b * 2 + 1) * CDIM + h * 32) * NPIX + n;
  const float* Prow = P + ((size_t)b * HEADS + h) * 1024;

  float vr[32];
  #pragma unroll
  for (int d = 0; d < 32; ++d) vr[d] = b2f(vb[(size_t)d * NPIX]);

  unsigned short ub[32];
  #pragma unroll
  for (int c = 0; c < 32; ++c) {
    const float4 p0 = *(const float4*)(Prow + c * 32 + 0);
    const float4 p1 = *(const float4*)(Prow + c * 32 + 4);
    const float4 p2 = *(const float4*)(Prow + c * 32 + 8);
    const float4 p3 = *(const float4*)(Prow + c * 32 + 12);
    const float4 p4 = *(const float4*)(Prow + c * 32 + 16);
    const float4 p5 = *(const float4*)(Prow + c * 32 + 20);
    const float4 p6 = *(const float4*)(Prow + c * 32 + 24);
    const float4 p7 = *(const float4*)(Prow + c * 32 + 28);
    float a = p0.x * vr[0]  + p0.y * vr[1]  + p0.z * vr[2]  + p0.w * vr[3]
            + p1.x * vr[4]  + p1.y * vr[5]  + p1.z * vr[6]  + p1.w * vr[7]
            + p2.x * vr[8]  + p2.y * vr[9]  + p2.z * vr[10] + p2.w * vr[11]
            + p3.x * vr[12] + p3.y * vr[13] + p3.z * vr[14] + p3.w * vr[15]
            + p4.x * vr[16] + p4.y * vr[17] + p4.z * vr[18] + p4.w * vr[19]
            + p5.x * vr[20] + p5.y * vr[21] + p5.z * vr[22] + p5.w * vr[23]
            + p6.x * vr[24] + p6.y * vr[25] + p6.z * vr[26] + p6.w * vr[27]
            + p7.x * vr[28] + p7.y * vr[29] + p7.z * vr[30] + p7.w * vr[31];
    float gg = b2f(gb[(size_t)c * NPIX]);
    float sg = 1.f / (1.f + expf(-gg));
    ub[c] = f2b(a * sg);
  }

  unsigned short* op = attT + (((size_t)(b * HEADS + h) * NPIX) + n) * 32;
  #pragma unroll
  for (int c8 = 0; c8 < 4; ++c8)
    *(u16x8*)(op + c8 * 8) = *(const u16x8*)(ub + c8 * 8);
}

extern "C" void kernel_launch(void* const* d_in, const int* in_sizes, int n_in,
                              void* d_out, int out_size, void* d_ws, size_t ws_size,
                              hipStream_t stream)
{
  const float* x      = (const float*)d_in[0];
  const float* qkv_w  = (const float*)d_in[1];
  const float* qkv_b  = (const float*)d_in[2];
  const float* dw_w   = (const float*)d_in[3];
  const float* dw_b   = (const float*)d_in[4];
  const float* temp   = (const float*)d_in[5];
  const float* proj_w = (const float*)d_in[6];
  const float* proj_b = (const float*)d_in[7];
  float* out = (float*)d_out;

  char* ws = (char*)d_ws;
  const size_t qbytes  = (size_t)CDIM * NPIX * 2;            // 25,165,824
  const size_t xTbytes = (size_t)2 * NPIX * PADC * 2;        // 52,428,800
  const size_t wbytes  = (size_t)5 * 192 * PADC * 2;         // 384,000
  unsigned short* xT    = (unsigned short*)ws;
  unsigned short* wbf   = (unsigned short*)(ws + xTbytes);
  unsigned short* pre   = (unsigned short*)(ws + xTbytes + wbytes);          // 4 slots
  unsigned short* post  = (unsigned short*)(ws + xTbytes + wbytes + 4 * qbytes);
  unsigned short* post2 = (unsigned short*)(ws + xTbytes + wbytes + 8 * qbytes);
  unsigned short* attT  = pre;                // [2][6][NPIX][32] = 50MB < 4q; pre dead
  float* S   = (float*)(ws + xTbytes + wbytes + 12 * qbytes);
  float* ssq = S + 2 * HEADS * 1024;
  float* P   = ssq + 2 * 2 * CDIM;
  const int nz = 2 * HEADS * 1024 + 2 * 2 * CDIM;

  zero_init<<<(nz + 255) / 256, 256, 0, stream>>>(S, nz);
  w2bf<<<(5 * 192 * 192 + 255) / 256, 256, 0, stream>>>(qkv_w, proj_w, wbf);
  x2t<<<dim3(NPIX / 64, 2), 256, 0, stream>>>(x, xT);

  const unsigned short* wq = wbf;                      // quarter stride 192*PADC
  const size_t wqs = (size_t)192 * PADC;

  // phase 1: q (quarter 0) + k (quarter 2), both batches -> pre slots b*2+{0,1}
  gemm_t<6, false, 0><<<dim3(NPIX / 64, 2), 256, 0, stream>>>(
      wq + 0 * wqs, wq + 2 * wqs, qkv_b + 0 * CDIM, qkv_b + 2 * CDIM, xT, pre);
  dwconv_ssq<<<dim3(CDIM * 8, 1, 4), 256, 0, stream>>>(pre, dw_w, dw_b, post, ssq, 0, 2);

  // phase 2: v (quarter 3) + gate (quarter 1) -> pre slots b*2+{0,1}
  gemm_t<6, false, 0><<<dim3(NPIX / 64, 2), 256, 0, stream>>>(
      wq + 3 * wqs, wq + 1 * wqs, qkv_b + 3 * CDIM, qkv_b + 1 * CDIM, xT, pre);
  dwconv_ssq<<<dim3(CDIM * 8, 1, 4), 256, 0, stream>>>(pre, dw_w, dw_b, post2, nullptr, 3, 1);

  gram<<<dim3(128, HEADS, 2), 256, 0, stream>>>(post, S);
  softmax_scale<<<dim3(HEADS, 2), 1024, 0, stream>>>(S, ssq, temp, P);

  // att -> attT (head-chunk layout, overlays pre)
  pv_gate<<<dim3(NPIX / 256, HEADS, 2), 256, 0, stream>>>(post2, P, attT);

  // proj: 3 m-tiles, BL=1 staging from attT, fp32 out c-major
  gemm_t<3, true, 1><<<dim3(NPIX / 64, 2), 256, 0, stream>>>(
      wq + 4 * wqs, wq + 4 * wqs, proj_b, proj_b, attT, out);
}